// Round 1
// baseline (644.344 us; speedup 1.0000x reference)
//
#include <hip/hip_runtime.h>

// OneHeadAttention: B=4, S=4096, D=256.
// out = [z (4*4096*256 fp32) | attn (4*4096*4096 fp32)]
//
// Pipeline (all bf16 MFMA 16x16x32, fp32 accum):
//  k_convert : q,k,v fp32 -> bf16
//  k_wt      : Wq/Wk/Wv/Wo fp32 [k][n] -> bf16 Wt [n][k]
//  k_gemm<true> x3 : projections -> qp,kp,vp bf16 [16384][256]
//  k_vt      : vp -> vpt [b][n][k] (for PV B-operand ds_read_b128)
//  k_qk      : E = exp(qp kp^T / 16) with causal zeroing, written fp32 into
//              the attn output slot; per-(b,ktile) partial row sums -> ps
//  k_pv      : row sums -> 1/sum; normalize E in place (final attn), P bf16,
//              ctx = P @ vp accumulated via MFMA (K-sweep stops at diagonal)
//  k_gemm<false> : z = ctx @ Wo + bo -> fp32 d_out

typedef unsigned short u16;
typedef __attribute__((ext_vector_type(8))) short short8;
typedef __attribute__((ext_vector_type(4))) float f32x4;

struct __align__(8) us4 { u16 x, y, z, w; };

#define SEQ 4096
#define DIM 256

__device__ __forceinline__ u16 f2bf(float f) {
  unsigned int u = __float_as_uint(f);
  u += 0x7fffu + ((u >> 16) & 1u);   // round-to-nearest-even
  return (u16)(u >> 16);
}

__device__ __forceinline__ void cp16(const void* g, void* l) {
  __builtin_amdgcn_global_load_lds((const __attribute__((address_space(1))) void*)g,
                                   (__attribute__((address_space(3))) void*)l, 16, 0, 0);
}

// ---------------- elementwise fp32 -> bf16 ----------------
__global__ void k_convert(const float* __restrict__ q, const float* __restrict__ k,
                          const float* __restrict__ v, u16* __restrict__ qb,
                          u16* __restrict__ kb, u16* __restrict__ vb) {
  const float* src = blockIdx.z == 0 ? q : (blockIdx.z == 1 ? k : v);
  u16* dst = blockIdx.z == 0 ? qb : (blockIdx.z == 1 ? kb : vb);
  size_t i4 = (size_t)blockIdx.x * 256 + threadIdx.x;
  float4 val = ((const float4*)src)[i4];
  us4 o;
  o.x = f2bf(val.x); o.y = f2bf(val.y); o.z = f2bf(val.z); o.w = f2bf(val.w);
  ((us4*)dst)[i4] = o;
}

// ---------------- weight transpose: Wt[n][k] = W[k][n], bf16 ----------------
__global__ void k_wt(const float* __restrict__ Wq, const float* __restrict__ Wk,
                     const float* __restrict__ Wv, const float* __restrict__ Wo,
                     u16* __restrict__ wt) {
  __shared__ float t[32][33];
  const float* W = blockIdx.z == 0 ? Wq : blockIdx.z == 1 ? Wk : blockIdx.z == 2 ? Wv : Wo;
  u16* out = wt + (size_t)blockIdx.z * 65536;
  int n0 = blockIdx.x * 32, k0 = blockIdx.y * 32;
  int tx = threadIdx.x, ty = threadIdx.y;
  for (int i = 0; i < 4; i++)
    t[ty + i * 8][tx] = W[(size_t)(k0 + ty + i * 8) * 256 + n0 + tx];
  __syncthreads();
  for (int i = 0; i < 4; i++)
    out[(size_t)(n0 + ty + i * 8) * 256 + k0 + tx] = f2bf(t[tx][ty + i * 8]);
}

// ---------------- vp transpose: vpt[b][n][k] = vp[b][k][n] ----------------
__global__ void k_vt(const u16* __restrict__ vp, u16* __restrict__ vpt) {
  __shared__ u16 t[32][33];
  int b = blockIdx.z;
  int n0 = blockIdx.x * 32, k0 = blockIdx.y * 32;
  int tx = threadIdx.x, ty = threadIdx.y;
  const u16* src = vp + ((size_t)b << 20);
  u16* dst = vpt + ((size_t)b << 20);
  for (int i = 0; i < 4; i++)
    t[ty + i * 8][tx] = src[(size_t)(k0 + ty + i * 8) * 256 + n0 + tx];
  __syncthreads();
  for (int i = 0; i < 4; i++)
    dst[(size_t)(n0 + ty + i * 8) * 4096 + k0 + tx] = t[tx][ty + i * 8];
}

// ---------------- generic 128x128-tile GEMM: out[m][n] = A[m][:] . Wt[n][:] + bias[n]
template <bool OUT_BF16>
__global__ void k_gemm(const u16* __restrict__ A, const u16* __restrict__ Wt,
                       const float* __restrict__ bias, void* __restrict__ outp) {
  __shared__ u16 Asm[128 * 32];
  __shared__ u16 Bsm[128 * 32];
  const int tid = threadIdx.x;
  const int lane = tid & 63, w = tid >> 6;
  const int wr = w >> 1, wc = w & 1;
  const int quad = lane >> 4, m16 = lane & 15;
  const int m0 = blockIdx.y * 128, n0 = blockIdx.x * 128;

  f32x4 zero = {0.f, 0.f, 0.f, 0.f};
  f32x4 acc[4][4];
  for (int i = 0; i < 4; i++)
    for (int j = 0; j < 4; j++) acc[i][j] = zero;

  for (int kk = 0; kk < 8; ++kk) {
    const int k0 = kk * 32;
    for (int h = 0; h < 2; ++h) {
      int c = tid + h * 256;
      int row = c >> 2, sub = c & 3;
      cp16(A + (size_t)(m0 + row) * 256 + k0 + sub * 8, Asm + c * 8);
      cp16(Wt + (size_t)(n0 + row) * 256 + k0 + sub * 8, Bsm + c * 8);
    }
    __syncthreads();
    short8 a[4], b[4];
    for (int i = 0; i < 4; ++i)
      a[i] = *(const short8*)(Asm + (wr * 64 + i * 16 + m16) * 32 + quad * 8);
    for (int j = 0; j < 4; ++j)
      b[j] = *(const short8*)(Bsm + (wc * 64 + j * 16 + m16) * 32 + quad * 8);
    for (int i = 0; i < 4; ++i)
      for (int j = 0; j < 4; ++j)
        acc[i][j] = __builtin_amdgcn_mfma_f32_16x16x32_bf16(a[i], b[j], acc[i][j], 0, 0, 0);
    __syncthreads();
  }

  for (int j = 0; j < 4; ++j) {
    int gn = n0 + wc * 64 + j * 16 + m16;
    float bv = bias[gn];
    for (int i = 0; i < 4; ++i) {
      int gm = m0 + wr * 64 + i * 16 + quad * 4;
      for (int r = 0; r < 4; ++r) {
        float val = acc[i][j][r] + bv;
        if (OUT_BF16)
          ((u16*)outp)[(size_t)(gm + r) * 256 + gn] = f2bf(val);
        else
          ((float*)outp)[(size_t)(gm + r) * 256 + gn] = val;
      }
    }
  }
}

// ---------------- QK^T, exp, causal zero, partial row sums ----------------
__global__ void k_qk(const u16* __restrict__ qp, const u16* __restrict__ kp,
                     float* __restrict__ attn, float* __restrict__ ps) {
  const int kt = blockIdx.x, qt = blockIdx.y, bz = blockIdx.z;
  const int tid = threadIdx.x;
  const int q0 = qt * 128, k0t = kt * 128;
  float* attnb = attn + ((size_t)bz << 24);

  if (kt > qt) {  // fully masked tile: zeros + zero partial sums
    float4 z4 = make_float4(0.f, 0.f, 0.f, 0.f);
    for (int s = 0; s < 16; ++s) {
      int idx = tid + s * 256;
      int row = idx >> 5, c4 = idx & 31;
      *(float4*)(attnb + (size_t)(q0 + row) * 4096 + k0t + c4 * 4) = z4;
    }
    if (tid < 128) ps[(size_t)(bz * 32 + kt) * 4096 + q0 + tid] = 0.f;
    return;
  }

  __shared__ u16 Asm[128 * 32];
  __shared__ u16 Bsm[128 * 32];
  __shared__ float prow[2][128];
  const int lane = tid & 63, w = tid >> 6;
  const int wr = w >> 1, wc = w & 1;
  const int quad = lane >> 4, m16 = lane & 15;
  const u16* Ab = qp + ((size_t)bz << 20);
  const u16* Bb = kp + ((size_t)bz << 20);

  f32x4 zero = {0.f, 0.f, 0.f, 0.f};
  f32x4 acc[4][4];
  for (int i = 0; i < 4; i++)
    for (int j = 0; j < 4; j++) acc[i][j] = zero;

  for (int kk = 0; kk < 8; ++kk) {
    const int k0 = kk * 32;
    for (int h = 0; h < 2; ++h) {
      int c = tid + h * 256;
      int row = c >> 2, sub = c & 3;
      cp16(Ab + (size_t)(q0 + row) * 256 + k0 + sub * 8, Asm + c * 8);
      cp16(Bb + (size_t)(k0t + row) * 256 + k0 + sub * 8, Bsm + c * 8);
    }
    __syncthreads();
    short8 a[4], b[4];
    for (int i = 0; i < 4; ++i)
      a[i] = *(const short8*)(Asm + (wr * 64 + i * 16 + m16) * 32 + quad * 8);
    for (int j = 0; j < 4; ++j)
      b[j] = *(const short8*)(Bsm + (wc * 64 + j * 16 + m16) * 32 + quad * 8);
    for (int i = 0; i < 4; ++i)
      for (int j = 0; j < 4; ++j)
        acc[i][j] = __builtin_amdgcn_mfma_f32_16x16x32_bf16(a[i], b[j], acc[i][j], 0, 0, 0);
    __syncthreads();
  }

  float rs[4][4];
  for (int i = 0; i < 4; i++)
    for (int r = 0; r < 4; r++) rs[i][r] = 0.f;

  for (int i = 0; i < 4; ++i) {
    int gq = q0 + wr * 64 + i * 16 + quad * 4;
    for (int j = 0; j < 4; ++j) {
      int gk = k0t + wc * 64 + j * 16 + m16;
      for (int r = 0; r < 4; ++r) {
        float e = 0.f;
        if (gk <= gq + r) e = __expf(acc[i][j][r] * 0.0625f);  // 1/sqrt(256)
        attnb[(size_t)(gq + r) * 4096 + gk] = e;  // unnormalized for now
        rs[i][r] += e;
      }
    }
  }
  // reduce row partials across the 16 lanes of each quad-row group
  for (int off = 1; off < 16; off <<= 1)
    for (int i = 0; i < 4; ++i)
      for (int r = 0; r < 4; ++r) rs[i][r] += __shfl_xor(rs[i][r], off, 64);
  if (m16 == 0)
    for (int i = 0; i < 4; ++i)
      for (int r = 0; r < 4; ++r)
        prow[wc][wr * 64 + i * 16 + quad * 4 + r] = rs[i][r];
  __syncthreads();
  if (tid < 128)
    ps[(size_t)(bz * 32 + kt) * 4096 + q0 + tid] = prow[0][tid] + prow[1][tid];
}

// ---------------- normalize (final attn) + PV matmul -> ctx bf16 ----------------
__global__ void k_pv(float* __restrict__ attn, const u16* __restrict__ vpt,
                     const float* __restrict__ ps, u16* __restrict__ ctx) {
  __shared__ u16 P_lds[64 * 32];
  __shared__ u16 V_lds[256 * 32];
  __shared__ float inv_lds[64];
  const int qt = blockIdx.x, bz = blockIdx.y;
  const int q0 = qt * 64;
  const int tid = threadIdx.x;
  const int lane = tid & 63, w = tid >> 6;
  const int quad = lane >> 4, m16 = lane & 15;
  float* attnb = attn + ((size_t)bz << 24);
  const u16* vb = vpt + ((size_t)bz << 20);

  if (tid < 64) {
    float s = 0.f;
    for (int kt = 0; kt < 32; ++kt)
      s += ps[(size_t)(bz * 32 + kt) * 4096 + q0 + tid];
    inv_lds[tid] = 1.f / s;
  }
  __syncthreads();

  f32x4 zero = {0.f, 0.f, 0.f, 0.f};
  f32x4 acc[4][4];
  for (int i = 0; i < 4; i++)
    for (int j = 0; j < 4; j++) acc[i][j] = zero;

  const int nch = q0 / 32 + 2;  // key chunks up to & including the diagonal
  for (int ck = 0; ck < nch; ++ck) {
    const int k0 = ck * 32;
    // stage V chunk [256 n][32 k] (async, 16B/lane)
    for (int hh = 0; hh < 4; ++hh) {
      int c = tid + hh * 256;
      int n = c >> 2, sub = c & 3;
      cp16(vb + (size_t)n * 4096 + k0 + sub * 8, V_lds + c * 8);
    }
    // load E chunk, normalize, write final attn in place, pack P bf16 to LDS
    for (int s = 0; s < 2; ++s) {
      int idx = tid + s * 256;
      int row = idx >> 3, c4 = idx & 7;
      float4* gp = (float4*)(attnb + (size_t)(q0 + row) * 4096 + k0 + c4 * 4);
      float4 e = *gp;
      float iv = inv_lds[row];
      e.x *= iv; e.y *= iv; e.z *= iv; e.w *= iv;
      *gp = e;
      us4 pk;
      pk.x = f2bf(e.x); pk.y = f2bf(e.y); pk.z = f2bf(e.z); pk.w = f2bf(e.w);
      *(us4*)(P_lds + row * 32 + c4 * 4) = pk;
    }
    __syncthreads();
    short8 a[4], b[4];
    for (int i = 0; i < 4; ++i)
      a[i] = *(const short8*)(P_lds + (i * 16 + m16) * 32 + quad * 8);
    for (int j = 0; j < 4; ++j)
      b[j] = *(const short8*)(V_lds + (w * 64 + j * 16 + m16) * 32 + quad * 8);
    for (int i = 0; i < 4; ++i)
      for (int j = 0; j < 4; ++j)
        acc[i][j] = __builtin_amdgcn_mfma_f32_16x16x32_bf16(a[i], b[j], acc[i][j], 0, 0, 0);
    __syncthreads();
  }

  u16* ctxb = ctx + ((size_t)bz * SEQ + q0) * 256;
  for (int i = 0; i < 4; ++i)
    for (int j = 0; j < 4; ++j) {
      int rl = i * 16 + quad * 4;
      int cn = w * 64 + j * 16 + m16;
      for (int r = 0; r < 4; ++r)
        ctxb[(size_t)(rl + r) * 256 + cn] = f2bf(acc[i][j][r]);
    }
}

extern "C" void kernel_launch(void* const* d_in, const int* in_sizes, int n_in,
                              void* d_out, int out_size, void* d_ws, size_t ws_size,
                              hipStream_t stream) {
  const float* q  = (const float*)d_in[0];
  const float* k  = (const float*)d_in[1];
  const float* v  = (const float*)d_in[2];
  const float* Wq = (const float*)d_in[4];
  const float* bq = (const float*)d_in[5];
  const float* Wk = (const float*)d_in[6];
  const float* bk = (const float*)d_in[7];
  const float* Wv = (const float*)d_in[8];
  const float* bv = (const float*)d_in[9];
  const float* Wo = (const float*)d_in[10];
  const float* bo = (const float*)d_in[11];

  const size_t MD = (size_t)16384 * 256;  // elements per [B*S, D] tensor
  u16* qb = (u16*)d_ws;
  u16* kb = qb + MD;
  u16* vb = kb + MD;
  u16* qp = vb + MD;
  u16* kp = qp + MD;
  u16* vp = kp + MD;
  u16* wt = vp + MD;                       // 4 x 256x256 bf16
  float* ps = (float*)(wt + 4 * 65536);    // [4][32][4096] fp32 partial row sums
  u16* vpt = kb;                           // reuse (kb dead after its projection)
  u16* ctx = qb;                           // reuse (qb dead after its projection)

  float* zout = (float*)d_out;
  float* attn = zout + (size_t)4 * 4096 * 256;

  k_convert<<<dim3(4096, 1, 3), 256, 0, stream>>>(q, k, v, qb, kb, vb);
  k_wt<<<dim3(8, 8, 4), dim3(32, 8), 0, stream>>>(Wq, Wk, Wv, Wo, wt);
  k_gemm<true><<<dim3(2, 128), 256, 0, stream>>>(qb, wt, bq, qp);
  k_gemm<true><<<dim3(2, 128), 256, 0, stream>>>(kb, wt + 65536, bk, kp);
  k_gemm<true><<<dim3(2, 128), 256, 0, stream>>>(vb, wt + 2 * 65536, bv, vp);
  k_vt<<<dim3(8, 128, 4), dim3(32, 8), 0, stream>>>(vp, vpt);
  k_qk<<<dim3(32, 32, 4), 256, 0, stream>>>(qp, kp, attn, ps);
  k_pv<<<dim3(64, 4), 256, 0, stream>>>(attn, vpt, ps, ctx);
  k_gemm<false><<<dim3(2, 128), 256, 0, stream>>>(ctx, wt + 3 * 65536, bo, zout);
}

// Round 2
// 595.429 us; speedup vs baseline: 1.0822x; 1.0822x over previous
//
#include <hip/hip_runtime.h>

// OneHeadAttention: B=4, S=4096, D=256.
// out = [z (4*4096*256 fp32) | attn (4*4096*4096 fp32)]
//
// Pipeline:
//  k_convert      : q,k,v fp32 -> bf16
//  k_wt           : W* fp32 [k][n] -> bf16 Wt [n][k]
//  k_gemm<true>x3 : projections -> qp,kp,vp bf16
//  k_vt           : vp -> vpt [b][n][k]
//  k_qk           : E = exp(qp kp^T/16) causal, unnormalized -> attn slot
//                   (epilogue via LDS transpose, float4 stores); ps partials
//  k_rsum         : inv[b][q] = 1/sum
//  k_zero         : ctxf = 0
//  k_pvg          : split-K PV: read E tile once, normalize+write final attn,
//                   pack P bf16, MFMA vs V, atomicAdd into ctxf fp32
//  k_cvt          : ctxf -> bf16
//  k_gemm<false>  : z = ctx @ Wo + bo

typedef unsigned short u16;
typedef __attribute__((ext_vector_type(8))) short short8;
typedef __attribute__((ext_vector_type(4))) float f32x4;

struct __align__(8) us4 { u16 x, y, z, w; };

#define SEQ 4096
#define DIM 256

__device__ __forceinline__ u16 f2bf(float f) {
  unsigned int u = __float_as_uint(f);
  u += 0x7fffu + ((u >> 16) & 1u);
  return (u16)(u >> 16);
}

__device__ __forceinline__ void cp16(const void* g, void* l) {
  __builtin_amdgcn_global_load_lds((const __attribute__((address_space(1))) void*)g,
                                   (__attribute__((address_space(3))) void*)l, 16, 0, 0);
}

// ---------------- elementwise fp32 -> bf16 ----------------
__global__ void k_convert(const float* __restrict__ q, const float* __restrict__ k,
                          const float* __restrict__ v, u16* __restrict__ qb,
                          u16* __restrict__ kb, u16* __restrict__ vb) {
  const float* src = blockIdx.z == 0 ? q : (blockIdx.z == 1 ? k : v);
  u16* dst = blockIdx.z == 0 ? qb : (blockIdx.z == 1 ? kb : vb);
  size_t i4 = (size_t)blockIdx.x * 256 + threadIdx.x;
  float4 val = ((const float4*)src)[i4];
  us4 o;
  o.x = f2bf(val.x); o.y = f2bf(val.y); o.z = f2bf(val.z); o.w = f2bf(val.w);
  ((us4*)dst)[i4] = o;
}

// ---------------- weight transpose ----------------
__global__ void k_wt(const float* __restrict__ Wq, const float* __restrict__ Wk,
                     const float* __restrict__ Wv, const float* __restrict__ Wo,
                     u16* __restrict__ wt) {
  __shared__ float t[32][33];
  const float* W = blockIdx.z == 0 ? Wq : blockIdx.z == 1 ? Wk : blockIdx.z == 2 ? Wv : Wo;
  u16* out = wt + (size_t)blockIdx.z * 65536;
  int n0 = blockIdx.x * 32, k0 = blockIdx.y * 32;
  int tx = threadIdx.x, ty = threadIdx.y;
  for (int i = 0; i < 4; i++)
    t[ty + i * 8][tx] = W[(size_t)(k0 + ty + i * 8) * 256 + n0 + tx];
  __syncthreads();
  for (int i = 0; i < 4; i++)
    out[(size_t)(n0 + ty + i * 8) * 256 + k0 + tx] = f2bf(t[tx][ty + i * 8]);
}

// ---------------- vp transpose ----------------
__global__ void k_vt(const u16* __restrict__ vp, u16* __restrict__ vpt) {
  __shared__ u16 t[32][33];
  int b = blockIdx.z;
  int n0 = blockIdx.x * 32, k0 = blockIdx.y * 32;
  int tx = threadIdx.x, ty = threadIdx.y;
  const u16* src = vp + ((size_t)b << 20);
  u16* dst = vpt + ((size_t)b << 20);
  for (int i = 0; i < 4; i++)
    t[ty + i * 8][tx] = src[(size_t)(k0 + ty + i * 8) * 256 + n0 + tx];
  __syncthreads();
  for (int i = 0; i < 4; i++)
    dst[(size_t)(n0 + ty + i * 8) * 4096 + k0 + tx] = t[tx][ty + i * 8];
}

// ---------------- generic 128x128 GEMM ----------------
template <bool OUT_BF16>
__global__ void k_gemm(const u16* __restrict__ A, const u16* __restrict__ Wt,
                       const float* __restrict__ bias, void* __restrict__ outp) {
  __shared__ u16 Asm[128 * 32];
  __shared__ u16 Bsm[128 * 32];
  const int tid = threadIdx.x;
  const int lane = tid & 63, w = tid >> 6;
  const int wr = w >> 1, wc = w & 1;
  const int quad = lane >> 4, m16 = lane & 15;
  const int m0 = blockIdx.y * 128, n0 = blockIdx.x * 128;

  f32x4 zero = {0.f, 0.f, 0.f, 0.f};
  f32x4 acc[4][4];
  for (int i = 0; i < 4; i++)
    for (int j = 0; j < 4; j++) acc[i][j] = zero;

  for (int kk = 0; kk < 8; ++kk) {
    const int k0 = kk * 32;
    for (int h = 0; h < 2; ++h) {
      int c = tid + h * 256;
      int row = c >> 2, sub = c & 3;
      cp16(A + (size_t)(m0 + row) * 256 + k0 + sub * 8, Asm + c * 8);
      cp16(Wt + (size_t)(n0 + row) * 256 + k0 + sub * 8, Bsm + c * 8);
    }
    __syncthreads();
    short8 a[4], b[4];
    for (int i = 0; i < 4; ++i)
      a[i] = *(const short8*)(Asm + (wr * 64 + i * 16 + m16) * 32 + quad * 8);
    for (int j = 0; j < 4; ++j)
      b[j] = *(const short8*)(Bsm + (wc * 64 + j * 16 + m16) * 32 + quad * 8);
    for (int i = 0; i < 4; ++i)
      for (int j = 0; j < 4; ++j)
        acc[i][j] = __builtin_amdgcn_mfma_f32_16x16x32_bf16(a[i], b[j], acc[i][j], 0, 0, 0);
    __syncthreads();
  }

  for (int j = 0; j < 4; ++j) {
    int gn = n0 + wc * 64 + j * 16 + m16;
    float bv = bias[gn];
    for (int i = 0; i < 4; ++i) {
      int gm = m0 + wr * 64 + i * 16 + quad * 4;
      for (int r = 0; r < 4; ++r) {
        float val = acc[i][j][r] + bv;
        if (OUT_BF16)
          ((u16*)outp)[(size_t)(gm + r) * 256 + gn] = f2bf(val);
        else
          ((float*)outp)[(size_t)(gm + r) * 256 + gn] = val;
      }
    }
  }
}

// ---------------- QK^T, exp, causal, LDS-transposed epilogue ----------------
__global__ void k_qk(const u16* __restrict__ qp, const u16* __restrict__ kp,
                     float* __restrict__ attn, float* __restrict__ ps) {
  const int kt = blockIdx.x, qt = blockIdx.y, bz = blockIdx.z;
  const int tid = threadIdx.x;
  const int q0 = qt * 128, k0t = kt * 128;
  float* attnb = attn + ((size_t)bz << 24);

  if (kt > qt) {  // fully masked: zeros + zero partial sums
    float4 z4 = make_float4(0.f, 0.f, 0.f, 0.f);
    for (int s = 0; s < 16; ++s) {
      int idx = tid + s * 256;
      int row = idx >> 5, c4 = idx & 31;
      *(float4*)(attnb + (size_t)(q0 + row) * 4096 + k0t + c4 * 4) = z4;
    }
    if (tid < 128) ps[(size_t)(bz * 32 + kt) * 4096 + q0 + tid] = 0.f;
    return;
  }

  __shared__ __align__(16) char smem[128 * 132 * 4];  // epi fp32 / staging union
  u16* Asm = (u16*)smem;
  u16* Bsm = Asm + 128 * 32;
  float* epi = (float*)smem;
  __shared__ float prow[2][128];

  const int lane = tid & 63, w = tid >> 6;
  const int wr = w >> 1, wc = w & 1;
  const int quad = lane >> 4, m16 = lane & 15;
  const u16* Ab = qp + ((size_t)bz << 20);
  const u16* Bb = kp + ((size_t)bz << 20);

  f32x4 zero = {0.f, 0.f, 0.f, 0.f};
  f32x4 acc[4][4];
  for (int i = 0; i < 4; i++)
    for (int j = 0; j < 4; j++) acc[i][j] = zero;

  for (int kk = 0; kk < 8; ++kk) {
    const int k0 = kk * 32;
    for (int h = 0; h < 2; ++h) {
      int c = tid + h * 256;
      int row = c >> 2, sub = c & 3;
      cp16(Ab + (size_t)(q0 + row) * 256 + k0 + sub * 8, Asm + c * 8);
      cp16(Bb + (size_t)(k0t + row) * 256 + k0 + sub * 8, Bsm + c * 8);
    }
    __syncthreads();
    short8 a[4], b[4];
    for (int i = 0; i < 4; ++i)
      a[i] = *(const short8*)(Asm + (wr * 64 + i * 16 + m16) * 32 + quad * 8);
    for (int j = 0; j < 4; ++j)
      b[j] = *(const short8*)(Bsm + (wc * 64 + j * 16 + m16) * 32 + quad * 8);
    for (int i = 0; i < 4; ++i)
      for (int j = 0; j < 4; ++j)
        acc[i][j] = __builtin_amdgcn_mfma_f32_16x16x32_bf16(a[i], b[j], acc[i][j], 0, 0, 0);
    __syncthreads();
  }

  // exp + causal mask (in place in acc) + row-sum partials
  float rs[4][4];
  for (int i = 0; i < 4; i++)
    for (int r = 0; r < 4; r++) rs[i][r] = 0.f;
  for (int i = 0; i < 4; ++i) {
    int gq = q0 + wr * 64 + i * 16 + quad * 4;
    for (int j = 0; j < 4; ++j) {
      int gk = k0t + wc * 64 + j * 16 + m16;
      for (int r = 0; r < 4; ++r) {
        float e = (gk <= gq + r) ? __expf(acc[i][j][r] * 0.0625f) : 0.f;
        acc[i][j][r] = e;
        rs[i][r] += e;
      }
    }
  }
  for (int off = 1; off < 16; off <<= 1)
    for (int i = 0; i < 4; ++i)
      for (int r = 0; r < 4; ++r) rs[i][r] += __shfl_xor(rs[i][r], off, 64);
  if (m16 == 0)
    for (int i = 0; i < 4; ++i)
      for (int r = 0; r < 4; ++r)
        prow[wc][wr * 64 + i * 16 + quad * 4 + r] = rs[i][r];

  // dump E into LDS (stride 132 to keep 2-way banks)
  for (int i = 0; i < 4; ++i)
    for (int j = 0; j < 4; ++j) {
      int rl = (wr * 64 + i * 16 + quad * 4) * 132 + wc * 64 + j * 16 + m16;
      for (int r = 0; r < 4; ++r) epi[rl + r * 132] = acc[i][j][r];
    }
  __syncthreads();

  // coalesced float4 store of the tile
  for (int it = 0; it < 16; ++it) {
    int idx = it * 256 + tid;
    int row = idx >> 5, c4 = idx & 31;
    float4 v4 = *(const float4*)(epi + row * 132 + c4 * 4);
    *(float4*)(attnb + (size_t)(q0 + row) * 4096 + k0t + c4 * 4) = v4;
  }
  if (tid < 128)
    ps[(size_t)(bz * 32 + kt) * 4096 + q0 + tid] = prow[0][tid] + prow[1][tid];
}

// ---------------- row-sum reduce -> inverse ----------------
__global__ void k_rsum(const float* __restrict__ ps, float* __restrict__ inv) {
  int b = blockIdx.y;
  int q = blockIdx.x * 256 + threadIdx.x;
  float s = 0.f;
  for (int kt = 0; kt < 32; ++kt) s += ps[(size_t)(b * 32 + kt) * 4096 + q];
  inv[b * 4096 + q] = 1.f / s;
}

// ---------------- zero ctxf ----------------
__global__ void k_zero(float4* __restrict__ p) {
  p[(size_t)blockIdx.x * 256 + threadIdx.x] = make_float4(0.f, 0.f, 0.f, 0.f);
}

// ---------------- split-K PV: normalize+write attn, MFMA vs V, atomic ctx ----------------
__global__ void __launch_bounds__(512) k_pvg(float* __restrict__ attn,
                                             const u16* __restrict__ vpt,
                                             const float* __restrict__ inv,
                                             float* __restrict__ ctxf) {
  const int kg = blockIdx.x, qt = blockIdx.y, bz = blockIdx.z;
  const int k_lo = kg * 1024;
  const int k_hi = min((qt + 1) * 128, k_lo + 1024);
  if (k_lo >= k_hi) return;

  __shared__ u16 P_lds[128 * 136];     // 34816 B (pad 8 -> 2-way banks)
  __shared__ u16 B_lds[2][256 * 32];   // 32768 B
  __shared__ float inv_lds[128];

  const int tid = threadIdx.x;
  const int lane = tid & 63, w = tid >> 6;
  const int wr = w >> 2, wc = w & 3;       // wr: q-half(64), wc: n-quarter(64)
  const int quad = lane >> 4, m16 = lane & 15;
  const int q0 = qt * 128;
  float* attnb = attn + ((size_t)bz << 24);
  const u16* vb = vpt + ((size_t)bz << 20);

  if (tid < 128) inv_lds[tid] = inv[bz * 4096 + q0 + tid];
  __syncthreads();

  f32x4 zero = {0.f, 0.f, 0.f, 0.f};
  f32x4 acc[4][4];
  for (int i = 0; i < 4; i++)
    for (int j = 0; j < 4; j++) acc[i][j] = zero;

  for (int kt0 = k_lo; kt0 < k_hi; kt0 += 128) {
    // read E tile, normalize, write final attn, pack bf16 P into LDS
    for (int p = 0; p < 8; ++p) {
      int idx = p * 512 + tid;
      int row = idx >> 5, c4 = idx & 31;
      float4* gp = (float4*)(attnb + (size_t)(q0 + row) * 4096 + kt0 + c4 * 4);
      float4 e = *gp;
      float ivr = inv_lds[row];
      e.x *= ivr; e.y *= ivr; e.z *= ivr; e.w *= ivr;
      *gp = e;
      us4 pk;
      pk.x = f2bf(e.x); pk.y = f2bf(e.y); pk.z = f2bf(e.z); pk.w = f2bf(e.w);
      *(us4*)(P_lds + row * 136 + c4 * 4) = pk;
    }
    for (int half = 0; half < 2; ++half) {
      if (half == 1) __syncthreads();  // readers of B_lds done
      // stage V: two 32-key buffers (256 n x 32 k each)
      for (int h = 0; h < 4; ++h) {
        int c = h * 512 + tid;          // 0..2047
        int sbuf = c >> 10;
        int cc = c & 1023;
        int n = cc >> 2, sub = cc & 3;
        cp16(vb + (size_t)n * 4096 + kt0 + half * 64 + sbuf * 32 + sub * 8,
             B_lds[sbuf] + n * 32 + sub * 8);
      }
      __syncthreads();  // staging (and P pack on half 0) visible
      for (int s = 0; s < 2; ++s) {
        int klocal = half * 64 + s * 32;
        short8 a[4], b[4];
        for (int i = 0; i < 4; ++i)
          a[i] = *(const short8*)(P_lds + (wr * 64 + i * 16 + m16) * 136 + klocal + quad * 8);
        for (int j = 0; j < 4; ++j)
          b[j] = *(const short8*)(B_lds[s] + (wc * 64 + j * 16 + m16) * 32 + quad * 8);
        for (int i = 0; i < 4; ++i)
          for (int j = 0; j < 4; ++j)
            acc[i][j] = __builtin_amdgcn_mfma_f32_16x16x32_bf16(a[i], b[j], acc[i][j], 0, 0, 0);
      }
    }
    __syncthreads();  // before P_lds / B_lds overwrite next tile
  }

  for (int i = 0; i < 4; ++i) {
    int gq = q0 + wr * 64 + i * 16 + quad * 4;
    for (int j = 0; j < 4; ++j) {
      int gn = wc * 64 + j * 16 + m16;
      for (int r = 0; r < 4; ++r)
        atomicAdd(&ctxf[((size_t)bz * 4096 + gq + r) * 256 + gn], acc[i][j][r]);
    }
  }
}

// ---------------- ctx fp32 -> bf16 ----------------
__global__ void k_cvt(const float* __restrict__ ctxf, u16* __restrict__ ctx) {
  size_t i4 = (size_t)blockIdx.x * 256 + threadIdx.x;
  float4 v = ((const float4*)ctxf)[i4];
  us4 o;
  o.x = f2bf(v.x); o.y = f2bf(v.y); o.z = f2bf(v.z); o.w = f2bf(v.w);
  ((us4*)ctx)[i4] = o;
}

extern "C" void kernel_launch(void* const* d_in, const int* in_sizes, int n_in,
                              void* d_out, int out_size, void* d_ws, size_t ws_size,
                              hipStream_t stream) {
  const float* q  = (const float*)d_in[0];
  const float* k  = (const float*)d_in[1];
  const float* v  = (const float*)d_in[2];
  const float* Wq = (const float*)d_in[4];
  const float* bq = (const float*)d_in[5];
  const float* Wk = (const float*)d_in[6];
  const float* bk = (const float*)d_in[7];
  const float* Wv = (const float*)d_in[8];
  const float* bv = (const float*)d_in[9];
  const float* Wo = (const float*)d_in[10];
  const float* bo = (const float*)d_in[11];

  const size_t MD = (size_t)16384 * 256;
  u16* qb = (u16*)d_ws;
  u16* kb = qb + MD;
  u16* vb = kb + MD;
  u16* qp = vb + MD;
  u16* kp = qp + MD;
  u16* vp = kp + MD;
  u16* wt = vp + MD;                         // 4 x 256x256 bf16
  float* ps   = (float*)(wt + 4 * 65536);    // [4][32][4096]
  float* inv  = ps + (size_t)4 * 32 * 4096;  // [4][4096]
  float* ctxf = inv + (size_t)4 * 4096;      // [4][4096][256] fp32
  u16* vpt = kb;  // reuse
  u16* ctx = qb;  // reuse

  float* zout = (float*)d_out;
  float* attn = zout + (size_t)4 * 4096 * 256;

  k_convert<<<dim3(4096, 1, 3), 256, 0, stream>>>(q, k, v, qb, kb, vb);
  k_wt<<<dim3(8, 8, 4), dim3(32, 8), 0, stream>>>(Wq, Wk, Wv, Wo, wt);
  k_gemm<true><<<dim3(2, 128), 256, 0, stream>>>(qb, wt, bq, qp);
  k_gemm<true><<<dim3(2, 128), 256, 0, stream>>>(kb, wt + 65536, bk, kp);
  k_gemm<true><<<dim3(2, 128), 256, 0, stream>>>(vb, wt + 2 * 65536, bv, vp);
  k_vt<<<dim3(8, 128, 4), dim3(32, 8), 0, stream>>>(vp, vpt);
  k_qk<<<dim3(32, 32, 4), 256, 0, stream>>>(qp, kp, attn, ps);
  k_rsum<<<dim3(16, 4), 256, 0, stream>>>(ps, inv);
  k_zero<<<4096, 256, 0, stream>>>((float4*)ctxf);
  k_pvg<<<dim3(4, 32, 4), 512, 0, stream>>>(attn, vpt, inv, ctxf);
  k_cvt<<<4096, 256, 0, stream>>>(ctxf, ctx);
  k_gemm<false><<<dim3(2, 128), 256, 0, stream>>>(ctx, wt + 3 * 65536, bo, zout);
}

// Round 3
// 580.331 us; speedup vs baseline: 1.1103x; 1.0260x over previous
//
#include <hip/hip_runtime.h>

// OneHeadAttention: B=4, S=4096, D=256.
// out = [z (4*4096*256 fp32) | attn (4*4096*4096 fp32)]
//
// Pipeline:
//  k_wt            : W* fp32 [k][n] -> bf16 Wt [n][k]
//  k_pgemm<false>x2: q,k fp32 -> (convert in-kernel) @ Wt + b -> qp,kp bf16
//  k_pgemm<true>   : v -> vp, epilogue transposes -> vpt [b][n][s] bf16
//  k_qk            : E = exp(qp kp^T/16) causal; lower tiles -> eb bf16 (ws),
//                    masked tiles -> attn zeros (nt); ps row-sum partials
//  k_rsum          : inv[b][q] = 1/sum
//  k_zero          : ctxf = 0
//  k_pv2           : split-K: read eb, P = inv*E (bf16), write final attn fp32
//                    once (nt), MFMA P@V, atomicAdd ctxf
//  k_cvt           : ctxf -> bf16 ctx
//  k_gemm<false>   : z = ctx @ Wo + bo

typedef unsigned short u16;
typedef __attribute__((ext_vector_type(8))) short short8;
typedef __attribute__((ext_vector_type(4))) float f32x4;
typedef __attribute__((ext_vector_type(4))) unsigned short u16x4;

struct __align__(8) us4 { u16 x, y, z, w; };

#define SEQ 4096
#define DIM 256

__device__ __forceinline__ u16 f2bf(float f) {
  unsigned int u = __float_as_uint(f);
  u += 0x7fffu + ((u >> 16) & 1u);
  return (u16)(u >> 16);
}
__device__ __forceinline__ float bf2f(u16 u) {
  return __uint_as_float(((unsigned int)u) << 16);
}

__device__ __forceinline__ void cp16(const void* g, void* l) {
  __builtin_amdgcn_global_load_lds((const __attribute__((address_space(1))) void*)g,
                                   (__attribute__((address_space(3))) void*)l, 16, 0, 0);
}

// ---------------- weight transpose ----------------
__global__ void k_wt(const float* __restrict__ Wq, const float* __restrict__ Wk,
                     const float* __restrict__ Wv, const float* __restrict__ Wo,
                     u16* __restrict__ wt) {
  __shared__ float t[32][33];
  const float* W = blockIdx.z == 0 ? Wq : blockIdx.z == 1 ? Wk : blockIdx.z == 2 ? Wv : Wo;
  u16* out = wt + (size_t)blockIdx.z * 65536;
  int n0 = blockIdx.x * 32, k0 = blockIdx.y * 32;
  int tx = threadIdx.x, ty = threadIdx.y;
  for (int i = 0; i < 4; i++)
    t[ty + i * 8][tx] = W[(size_t)(k0 + ty + i * 8) * 256 + n0 + tx];
  __syncthreads();
  for (int i = 0; i < 4; i++)
    out[(size_t)(n0 + ty + i * 8) * 256 + k0 + tx] = f2bf(t[tx][ty + i * 8]);
}

// ---------------- projection GEMM: A fp32 -> bf16 in-kernel ----------------
// out[m][n] = A[m][:] . Wt[n][:] + bias[n].  TRANS: write vpt[b][n][s] instead.
template <bool TRANS>
__global__ void k_pgemm(const float* __restrict__ A, const u16* __restrict__ Wt,
                        const float* __restrict__ bias, u16* __restrict__ outp) {
  __shared__ __align__(16) char smem[34816];  // staging 16KB | TRANS epi 34816B
  u16* Asm = (u16*)smem;
  u16* Bsm = Asm + 4096;
  u16* tb = (u16*)smem;
  const int tid = threadIdx.x;
  const int lane = tid & 63, w = tid >> 6;
  const int wr = w >> 1, wc = w & 1;
  const int quad = lane >> 4, m16 = lane & 15;
  const int m0 = blockIdx.y * 128, n0 = blockIdx.x * 128;

  f32x4 zero = {0.f, 0.f, 0.f, 0.f};
  f32x4 acc[4][4];
  for (int i = 0; i < 4; i++)
    for (int j = 0; j < 4; j++) acc[i][j] = zero;

  for (int kk = 0; kk < 8; ++kk) {
    const int k0 = kk * 32;
    for (int h = 0; h < 2; ++h) {
      int c = tid + h * 256;
      int row = c >> 2, sub = c & 3;
      cp16(Wt + (size_t)(n0 + row) * 256 + k0 + sub * 8, Bsm + c * 8);
    }
    for (int h = 0; h < 4; ++h) {
      int idx = h * 256 + tid;
      int row = idx >> 3, q4 = idx & 7;
      float4 a4 = *(const float4*)(A + (size_t)(m0 + row) * 256 + k0 + q4 * 4);
      us4 o;
      o.x = f2bf(a4.x); o.y = f2bf(a4.y); o.z = f2bf(a4.z); o.w = f2bf(a4.w);
      *(us4*)(Asm + row * 32 + q4 * 4) = o;
    }
    __syncthreads();
    short8 a[4], b[4];
    for (int i = 0; i < 4; ++i)
      a[i] = *(const short8*)(Asm + (wr * 64 + i * 16 + m16) * 32 + quad * 8);
    for (int j = 0; j < 4; ++j)
      b[j] = *(const short8*)(Bsm + (wc * 64 + j * 16 + m16) * 32 + quad * 8);
    for (int i = 0; i < 4; ++i)
      for (int j = 0; j < 4; ++j)
        acc[i][j] = __builtin_amdgcn_mfma_f32_16x16x32_bf16(a[i], b[j], acc[i][j], 0, 0, 0);
    __syncthreads();
  }

  if (!TRANS) {
    for (int j = 0; j < 4; ++j) {
      int gn = n0 + wc * 64 + j * 16 + m16;
      float bv = bias[gn];
      for (int i = 0; i < 4; ++i) {
        int gm = m0 + wr * 64 + i * 16 + quad * 4;
        for (int r = 0; r < 4; ++r)
          outp[(size_t)(gm + r) * 256 + gn] = f2bf(acc[i][j][r] + bv);
      }
    }
  } else {
    // transpose epilogue -> vpt[b][n][s]
    for (int j = 0; j < 4; ++j) {
      int cn = wc * 64 + j * 16 + m16;
      float bv = bias[n0 + cn];
      for (int i = 0; i < 4; ++i) {
        int rm = wr * 64 + i * 16 + quad * 4;
        us4 o;
        o.x = f2bf(acc[i][j][0] + bv); o.y = f2bf(acc[i][j][1] + bv);
        o.z = f2bf(acc[i][j][2] + bv); o.w = f2bf(acc[i][j][3] + bv);
        *(us4*)(tb + cn * 136 + rm) = o;
      }
    }
    __syncthreads();
    int b = m0 >> 12, s0 = m0 & 4095;
    u16* dst = outp + ((size_t)b << 20);
    for (int it = 0; it < 8; ++it) {
      int idx = it * 256 + tid;
      int n = idx >> 4, m8 = idx & 15;
      short8 v8 = *(const short8*)(tb + n * 136 + m8 * 8);
      *(short8*)(dst + (size_t)(n0 + n) * 4096 + s0 + m8 * 8) = v8;
    }
  }
}

// ---------------- QK^T, exp, causal; eb bf16 (lower) / attn zeros (upper) ----
__global__ void k_qk(const u16* __restrict__ qp, const u16* __restrict__ kp,
                     u16* __restrict__ eb, float* __restrict__ attn,
                     float* __restrict__ ps) {
  const int kt = blockIdx.x, qt = blockIdx.y, bz = blockIdx.z;
  const int tid = threadIdx.x;
  const int q0 = qt * 128, k0t = kt * 128;

  if (kt > qt) {  // fully masked: attn zeros + zero partial sums
    float* attnb = attn + ((size_t)bz << 24);
    f32x4 z4 = {0.f, 0.f, 0.f, 0.f};
    for (int s = 0; s < 16; ++s) {
      int idx = tid + s * 256;
      int row = idx >> 5, c4 = idx & 31;
      __builtin_nontemporal_store(z4,
          (f32x4*)(attnb + (size_t)(q0 + row) * 4096 + k0t + c4 * 4));
    }
    if (tid < 128) ps[(size_t)(bz * 32 + kt) * 4096 + q0 + tid] = 0.f;
    return;
  }

  __shared__ __align__(16) char smem[34816];  // staging 16KB | epi u16 128x136
  u16* Asm = (u16*)smem;
  u16* Bsm = Asm + 4096;
  u16* epi = (u16*)smem;
  __shared__ float prow[2][128];

  const int lane = tid & 63, w = tid >> 6;
  const int wr = w >> 1, wc = w & 1;
  const int quad = lane >> 4, m16 = lane & 15;
  const u16* Ab = qp + ((size_t)bz << 20);
  const u16* Bb = kp + ((size_t)bz << 20);

  f32x4 zero = {0.f, 0.f, 0.f, 0.f};
  f32x4 acc[4][4];
  for (int i = 0; i < 4; i++)
    for (int j = 0; j < 4; j++) acc[i][j] = zero;

  for (int kk = 0; kk < 8; ++kk) {
    const int k0 = kk * 32;
    for (int h = 0; h < 2; ++h) {
      int c = tid + h * 256;
      int row = c >> 2, sub = c & 3;
      cp16(Ab + (size_t)(q0 + row) * 256 + k0 + sub * 8, Asm + c * 8);
      cp16(Bb + (size_t)(k0t + row) * 256 + k0 + sub * 8, Bsm + c * 8);
    }
    __syncthreads();
    short8 a[4], b[4];
    for (int i = 0; i < 4; ++i)
      a[i] = *(const short8*)(Asm + (wr * 64 + i * 16 + m16) * 32 + quad * 8);
    for (int j = 0; j < 4; ++j)
      b[j] = *(const short8*)(Bsm + (wc * 64 + j * 16 + m16) * 32 + quad * 8);
    for (int i = 0; i < 4; ++i)
      for (int j = 0; j < 4; ++j)
        acc[i][j] = __builtin_amdgcn_mfma_f32_16x16x32_bf16(a[i], b[j], acc[i][j], 0, 0, 0);
    __syncthreads();
  }

  // exp + causal mask + row-sum partials
  float rs[4][4];
  for (int i = 0; i < 4; i++)
    for (int r = 0; r < 4; r++) rs[i][r] = 0.f;
  for (int i = 0; i < 4; ++i) {
    int gq = q0 + wr * 64 + i * 16 + quad * 4;
    for (int j = 0; j < 4; ++j) {
      int gk = k0t + wc * 64 + j * 16 + m16;
      for (int r = 0; r < 4; ++r) {
        float e = (gk <= gq + r) ? __expf(acc[i][j][r] * 0.0625f) : 0.f;
        acc[i][j][r] = e;
        rs[i][r] += e;
      }
    }
  }
  for (int off = 1; off < 16; off <<= 1)
    for (int i = 0; i < 4; ++i)
      for (int r = 0; r < 4; ++r) rs[i][r] += __shfl_xor(rs[i][r], off, 64);
  if (m16 == 0)
    for (int i = 0; i < 4; ++i)
      for (int r = 0; r < 4; ++r)
        prow[wc][wr * 64 + i * 16 + quad * 4 + r] = rs[i][r];

  // dump E bf16 into LDS, then coalesced 16B nt stores to eb
  for (int i = 0; i < 4; ++i)
    for (int j = 0; j < 4; ++j) {
      int rl = wr * 64 + i * 16 + quad * 4;
      int cl = wc * 64 + j * 16 + m16;
      for (int r = 0; r < 4; ++r) epi[(rl + r) * 136 + cl] = f2bf(acc[i][j][r]);
    }
  __syncthreads();

  u16* ebb = eb + ((size_t)bz << 24);
  for (int it = 0; it < 8; ++it) {
    int idx = it * 256 + tid;
    int row = idx >> 4, m8 = idx & 15;
    short8 v8 = *(const short8*)(epi + row * 136 + m8 * 8);
    __builtin_nontemporal_store(v8,
        (short8*)(ebb + (size_t)(q0 + row) * 4096 + k0t + m8 * 8));
  }
  if (tid < 128)
    ps[(size_t)(bz * 32 + kt) * 4096 + q0 + tid] = prow[0][tid] + prow[1][tid];
}

// ---------------- row-sum reduce -> inverse ----------------
__global__ void k_rsum(const float* __restrict__ ps, float* __restrict__ inv) {
  int b = blockIdx.y;
  int q = blockIdx.x * 256 + threadIdx.x;
  float s = 0.f;
  for (int kt = 0; kt < 32; ++kt) s += ps[(size_t)(b * 32 + kt) * 4096 + q];
  inv[b * 4096 + q] = 1.f / s;
}

// ---------------- zero ctxf ----------------
__global__ void k_zero(float4* __restrict__ p) {
  p[(size_t)blockIdx.x * 256 + threadIdx.x] = make_float4(0.f, 0.f, 0.f, 0.f);
}

// ---------------- split-K PV: read eb, write final attn, MFMA, atomic ctx ----
__global__ void __launch_bounds__(512) k_pv2(const u16* __restrict__ eb,
                                             const u16* __restrict__ vpt,
                                             const float* __restrict__ inv,
                                             float* __restrict__ attn,
                                             float* __restrict__ ctxf) {
  const int kg = blockIdx.x, qt = blockIdx.y, bz = blockIdx.z;
  const int k_lo = kg * 1024;
  const int k_hi = min((qt + 1) * 128, k_lo + 1024);
  if (k_lo >= k_hi) return;

  __shared__ u16 P_lds[128 * 136];     // 34816 B
  __shared__ u16 B_lds[2][256 * 32];   // 32768 B
  __shared__ float inv_lds[128];

  const int tid = threadIdx.x;
  const int lane = tid & 63, w = tid >> 6;
  const int wr = w >> 2, wc = w & 3;       // wr: q-half(64), wc: n-quarter(64)
  const int quad = lane >> 4, m16 = lane & 15;
  const int q0 = qt * 128;
  const u16* ebb = eb + ((size_t)bz << 24);
  float* attnb = attn + ((size_t)bz << 24);
  const u16* vb = vpt + ((size_t)bz << 20);

  if (tid < 128) inv_lds[tid] = inv[bz * 4096 + q0 + tid];
  __syncthreads();

  f32x4 zero = {0.f, 0.f, 0.f, 0.f};
  f32x4 acc[4][4];
  for (int i = 0; i < 4; i++)
    for (int j = 0; j < 4; j++) acc[i][j] = zero;

  for (int kt0 = k_lo; kt0 < k_hi; kt0 += 128) {
    // read E bf16, P = inv*E: write attn fp32 (nt) + pack P bf16 into LDS
    for (int p = 0; p < 8; ++p) {
      int idx = p * 512 + tid;
      int row = idx >> 5, c4 = idx & 31;
      u16x4 e4 = __builtin_nontemporal_load(
          (const u16x4*)(ebb + (size_t)(q0 + row) * 4096 + kt0 + c4 * 4));
      float ivr = inv_lds[row];
      f32x4 pv;
      us4 pk;
      pk.x = f2bf(bf2f(e4[0]) * ivr); pv[0] = bf2f(pk.x);
      pk.y = f2bf(bf2f(e4[1]) * ivr); pv[1] = bf2f(pk.y);
      pk.z = f2bf(bf2f(e4[2]) * ivr); pv[2] = bf2f(pk.z);
      pk.w = f2bf(bf2f(e4[3]) * ivr); pv[3] = bf2f(pk.w);
      *(us4*)(P_lds + row * 136 + c4 * 4) = pk;
      __builtin_nontemporal_store(pv,
          (f32x4*)(attnb + (size_t)(q0 + row) * 4096 + kt0 + c4 * 4));
    }
    for (int half = 0; half < 2; ++half) {
      if (half == 1) __syncthreads();  // readers of B_lds done
      for (int h = 0; h < 4; ++h) {
        int c = h * 512 + tid;          // 0..2047
        int sbuf = c >> 10;
        int cc = c & 1023;
        int n = cc >> 2, sub = cc & 3;
        cp16(vb + (size_t)n * 4096 + kt0 + half * 64 + sbuf * 32 + sub * 8,
             B_lds[sbuf] + n * 32 + sub * 8);
      }
      __syncthreads();  // staging (and P pack on half 0) visible
      for (int s = 0; s < 2; ++s) {
        int klocal = half * 64 + s * 32;
        short8 a[4], b[4];
        for (int i = 0; i < 4; ++i)
          a[i] = *(const short8*)(P_lds + (wr * 64 + i * 16 + m16) * 136 + klocal + quad * 8);
        for (int j = 0; j < 4; ++j)
          b[j] = *(const short8*)(B_lds[s] + (wc * 64 + j * 16 + m16) * 32 + quad * 8);
        for (int i = 0; i < 4; ++i)
          for (int j = 0; j < 4; ++j)
            acc[i][j] = __builtin_amdgcn_mfma_f32_16x16x32_bf16(a[i], b[j], acc[i][j], 0, 0, 0);
      }
    }
    __syncthreads();  // before P_lds / B_lds overwrite next tile
  }

  for (int i = 0; i < 4; ++i) {
    int gq = q0 + wr * 64 + i * 16 + quad * 4;
    for (int j = 0; j < 4; ++j) {
      int gn = wc * 64 + j * 16 + m16;
      for (int r = 0; r < 4; ++r)
        atomicAdd(&ctxf[((size_t)bz * 4096 + gq + r) * 256 + gn], acc[i][j][r]);
    }
  }
}

// ---------------- ctx fp32 -> bf16 ----------------
__global__ void k_cvt(const float* __restrict__ ctxf, u16* __restrict__ ctx) {
  size_t i4 = (size_t)blockIdx.x * 256 + threadIdx.x;
  float4 v = ((const float4*)ctxf)[i4];
  us4 o;
  o.x = f2bf(v.x); o.y = f2bf(v.y); o.z = f2bf(v.z); o.w = f2bf(v.w);
  ((us4*)ctx)[i4] = o;
}

// ---------------- bf16-input GEMM (final projection) ----------------
template <bool OUT_BF16>
__global__ void k_gemm(const u16* __restrict__ A, const u16* __restrict__ Wt,
                       const float* __restrict__ bias, void* __restrict__ outp) {
  __shared__ u16 Asm[128 * 32];
  __shared__ u16 Bsm[128 * 32];
  const int tid = threadIdx.x;
  const int lane = tid & 63, w = tid >> 6;
  const int wr = w >> 1, wc = w & 1;
  const int quad = lane >> 4, m16 = lane & 15;
  const int m0 = blockIdx.y * 128, n0 = blockIdx.x * 128;

  f32x4 zero = {0.f, 0.f, 0.f, 0.f};
  f32x4 acc[4][4];
  for (int i = 0; i < 4; i++)
    for (int j = 0; j < 4; j++) acc[i][j] = zero;

  for (int kk = 0; kk < 8; ++kk) {
    const int k0 = kk * 32;
    for (int h = 0; h < 2; ++h) {
      int c = tid + h * 256;
      int row = c >> 2, sub = c & 3;
      cp16(A + (size_t)(m0 + row) * 256 + k0 + sub * 8, Asm + c * 8);
      cp16(Wt + (size_t)(n0 + row) * 256 + k0 + sub * 8, Bsm + c * 8);
    }
    __syncthreads();
    short8 a[4], b[4];
    for (int i = 0; i < 4; ++i)
      a[i] = *(const short8*)(Asm + (wr * 64 + i * 16 + m16) * 32 + quad * 8);
    for (int j = 0; j < 4; ++j)
      b[j] = *(const short8*)(Bsm + (wc * 64 + j * 16 + m16) * 32 + quad * 8);
    for (int i = 0; i < 4; ++i)
      for (int j = 0; j < 4; ++j)
        acc[i][j] = __builtin_amdgcn_mfma_f32_16x16x32_bf16(a[i], b[j], acc[i][j], 0, 0, 0);
    __syncthreads();
  }

  for (int j = 0; j < 4; ++j) {
    int gn = n0 + wc * 64 + j * 16 + m16;
    float bv = bias[gn];
    for (int i = 0; i < 4; ++i) {
      int gm = m0 + wr * 64 + i * 16 + quad * 4;
      for (int r = 0; r < 4; ++r) {
        float val = acc[i][j][r] + bv;
        if (OUT_BF16)
          ((u16*)outp)[(size_t)(gm + r) * 256 + gn] = f2bf(val);
        else
          ((float*)outp)[(size_t)(gm + r) * 256 + gn] = val;
      }
    }
  }
}

extern "C" void kernel_launch(void* const* d_in, const int* in_sizes, int n_in,
                              void* d_out, int out_size, void* d_ws, size_t ws_size,
                              hipStream_t stream) {
  const float* q  = (const float*)d_in[0];
  const float* k  = (const float*)d_in[1];
  const float* v  = (const float*)d_in[2];
  const float* Wq = (const float*)d_in[4];
  const float* bq = (const float*)d_in[5];
  const float* Wk = (const float*)d_in[6];
  const float* bk = (const float*)d_in[7];
  const float* Wv = (const float*)d_in[8];
  const float* bv = (const float*)d_in[9];
  const float* Wo = (const float*)d_in[10];
  const float* bo = (const float*)d_in[11];

  const size_t MD = (size_t)16384 * 256;
  u16* qp  = (u16*)d_ws;
  u16* kp  = qp + MD;
  u16* vpt = kp + MD;                         // [4][256][4096]
  u16* ctx = vpt + MD;
  u16* wt  = ctx + MD;                        // 4 x 256x256 bf16
  float* ps   = (float*)(wt + 4 * 65536);     // [4][32][4096]
  float* inv  = ps + (size_t)4 * 32 * 4096;   // [4][4096]
  float* ctxf = inv + (size_t)4 * 4096;       // [4][4096][256] fp32
  u16* eb = (u16*)(ctxf + MD);                // [4][4096][4096] bf16 unnormalized E

  float* zout = (float*)d_out;
  float* attn = zout + (size_t)4 * 4096 * 256;

  k_wt<<<dim3(8, 8, 4), dim3(32, 8), 0, stream>>>(Wq, Wk, Wv, Wo, wt);
  k_pgemm<false><<<dim3(2, 128), 256, 0, stream>>>(q, wt, bq, qp);
  k_pgemm<false><<<dim3(2, 128), 256, 0, stream>>>(k, wt + 65536, bk, kp);
  k_pgemm<true><<<dim3(2, 128), 256, 0, stream>>>(v, wt + 2 * 65536, bv, vpt);
  k_qk<<<dim3(32, 32, 4), 256, 0, stream>>>(qp, kp, eb, attn, ps);
  k_rsum<<<dim3(16, 4), 256, 0, stream>>>(ps, inv);
  k_zero<<<4096, 256, 0, stream>>>((float4*)ctxf);
  k_pv2<<<dim3(4, 32, 4), 512, 0, stream>>>(eb, vpt, inv, attn, ctxf);
  k_cvt<<<4096, 256, 0, stream>>>(ctxf, ctx);
  k_gemm<false><<<dim3(2, 128), 256, 0, stream>>>(ctx, wt + 3 * 65536, bo, zout);
}